// Round 3
// baseline (346.425 us; speedup 1.0000x reference)
//
#include <hip/hip_runtime.h>
#include <hip/hip_bf16.h>
#include <math.h>

// Problem constants
#define B_ 8
#define S_ 4096
#define E_ 1024
#define H_ 128
#define MIN_K 32
// d_out layout: filtered [B,S,E] | selection_mask [B,S] | expected_k [B]
#define OUT_MASK_OFF (B_*S_*E_)
#define OUT_EK_OFF   (B_*S_*E_ + B_*S_)

// workspace byte offsets
#define Z_OFF      0
#define SOFT_OFF   131072
#define CNT_OFF    262144
#define KROW_OFF   393216
#define PARTS_OFF  393248   // 8-aligned, 512 doubles
#define PARTM_OFF  397344   // 512 floats
#define W1T_HI_OFF 399392   // 16-aligned
#define W1T_LO_OFF 661536   // 16-aligned

typedef __attribute__((ext_vector_type(8))) short   frag8;   // 8 bf16 (4 VGPR)
typedef __attribute__((ext_vector_type(4))) float   fragc;   // 4 f32 acc
typedef __attribute__((ext_vector_type(4))) unsigned short us4;

static __device__ __forceinline__ unsigned short bf16_rne(float f) {
  unsigned u = __float_as_uint(f);
  unsigned r = u + 0x7FFF + ((u >> 16) & 1);
  return (unsigned short)(r >> 16);
}
static __device__ __forceinline__ float bf16_to_f32(unsigned short h) {
  return __uint_as_float(((unsigned)h) << 16);
}

// ---------------------------------------------------------------------------
// Prep: w1 [E][H] f32 -> w1t_hi/lo [H][E] bf16 (transposed, k-contiguous)
// ---------------------------------------------------------------------------
__global__ __launch_bounds__(256) void prep_w_kernel(
    const float* __restrict__ w1,
    unsigned short* __restrict__ w1t_hi, unsigned short* __restrict__ w1t_lo)
{
  int id = blockIdx.x * 256 + threadIdx.x;       // 0..32767
  int k  = id >> 5;                               // 0..1023
  int n4 = id & 31;                               // 0..31
  float4 w = *(const float4*)(w1 + k * H_ + n4 * 4);
#pragma unroll
  for (int e = 0; e < 4; ++e) {
    float f = (e == 0) ? w.x : (e == 1) ? w.y : (e == 2) ? w.z : w.w;
    unsigned short hi = bf16_rne(f);
    unsigned short lo = bf16_rne(f - bf16_to_f32(hi));
    int n = n4 * 4 + e;
    w1t_hi[n * E_ + k] = hi;
    w1t_lo[n * E_ + k] = lo;
  }
}

// ---------------------------------------------------------------------------
// Scorer: split-bf16 MFMA (3 products), square register tiling.
// Block 256 thr = 4 waves in a 2x2 grid (wr=wave>>1, wc=wave&1).
// Tile M=128, N=128, KT=32. Wave: mt=4 m-tiles (rows wr*64..+64),
// nt=4 n-tiles (n wc*64..+64). Both A and B staged in LDS; per-MFMA LDS
// traffic = (1/4+1/4) KB -> ~3.3x MFMA-time model (vs 5x in round 2).
// Epilogue fuses logit reduce + gumbel z + sigmoid/max partials (shfl trees).
// ---------------------------------------------------------------------------
#define KT 32
#define LDST 40   // shorts; 80 B row stride = 5*16B (aligned, 2-way banks)

__global__ __launch_bounds__(256) void scorer_kernel(
    const float* __restrict__ x,
    const unsigned short* __restrict__ w1t_hi,
    const unsigned short* __restrict__ w1t_lo,
    const float* __restrict__ b1, const float* __restrict__ w2,
    const float* __restrict__ b2, const float* __restrict__ u,
    float* __restrict__ zout, double* __restrict__ partS,
    float* __restrict__ partM)
{
  __shared__ unsigned short xs_hi[128 * LDST];
  __shared__ unsigned short xs_lo[128 * LDST];
  __shared__ unsigned short bs_hi[128 * LDST];
  __shared__ unsigned short bs_lo[128 * LDST];
  __shared__ float part[4][64];

  const int tid  = threadIdx.x;
  const int wave = tid >> 6;
  const int lane = tid & 63;
  const int l15  = lane & 15;
  const int quad = lane >> 4;
  const int wr   = wave >> 1;
  const int wc   = wave & 1;
  const int m0   = blockIdx.x * 128;

  fragc acc[4][4];
#pragma unroll
  for (int i = 0; i < 4; ++i)
#pragma unroll
    for (int j = 0; j < 4; ++j) acc[i][j] = (fragc)(0.f);

  // x staging map: 1024 float4 per tile, 4 per thread
  int sm[4], skq[4];
#pragma unroll
  for (int i = 0; i < 4; ++i) { int idx = tid + i * 256; sm[i] = idx >> 3; skq[i] = idx & 7; }
  // B staging map: 512 16B-loads per array, 2 per thread
  int bn[2], bkq[2];
#pragma unroll
  for (int i = 0; i < 2; ++i) { int idx = tid + i * 256; bn[i] = idx >> 2; bkq[i] = idx & 3; }

  float4 p[4];
  uint4  qh[2], ql[2];
#pragma unroll
  for (int i = 0; i < 4; ++i)
    p[i] = *(const float4*)(x + (size_t)(m0 + sm[i]) * E_ + skq[i] * 4);
#pragma unroll
  for (int i = 0; i < 2; ++i) {
    size_t off = (size_t)bn[i] * E_ + bkq[i] * 8;
    qh[i] = *(const uint4*)(w1t_hi + off);
    ql[i] = *(const uint4*)(w1t_lo + off);
  }

  for (int k0 = 0; k0 < E_; k0 += KT) {
    __syncthreads();   // previous tile fully consumed
#pragma unroll
    for (int i = 0; i < 4; ++i) {
      us4 h4, l4;
      float fv[4] = {p[i].x, p[i].y, p[i].z, p[i].w};
#pragma unroll
      for (int e = 0; e < 4; ++e) {
        unsigned short hi = bf16_rne(fv[e]);
        h4[e] = hi; l4[e] = bf16_rne(fv[e] - bf16_to_f32(hi));
      }
      *(us4*)&xs_hi[sm[i] * LDST + skq[i] * 4] = h4;
      *(us4*)&xs_lo[sm[i] * LDST + skq[i] * 4] = l4;
    }
#pragma unroll
    for (int i = 0; i < 2; ++i) {
      *(uint4*)&bs_hi[bn[i] * LDST + bkq[i] * 8] = qh[i];
      *(uint4*)&bs_lo[bn[i] * LDST + bkq[i] * 8] = ql[i];
    }
    __syncthreads();

    if (k0 + KT < E_) {
#pragma unroll
      for (int i = 0; i < 4; ++i)
        p[i] = *(const float4*)(x + (size_t)(m0 + sm[i]) * E_ + (k0 + KT) + skq[i] * 4);
#pragma unroll
      for (int i = 0; i < 2; ++i) {
        size_t off = (size_t)bn[i] * E_ + (k0 + KT) + bkq[i] * 8;
        qh[i] = *(const uint4*)(w1t_hi + off);
        ql[i] = *(const uint4*)(w1t_lo + off);
      }
    }

    frag8 bh[4], bl[4];
#pragma unroll
    for (int ntl = 0; ntl < 4; ++ntl) {
      int a = ((wc * 4 + ntl) * 16 + l15) * LDST + quad * 8;
      bh[ntl] = *(const frag8*)&bs_hi[a];
      bl[ntl] = *(const frag8*)&bs_lo[a];
    }
#pragma unroll
    for (int mtl = 0; mtl < 4; ++mtl) {
      int a = ((wr * 4 + mtl) * 16 + l15) * LDST + quad * 8;
      frag8 ah = *(const frag8*)&xs_hi[a];
      frag8 al = *(const frag8*)&xs_lo[a];
#pragma unroll
      for (int ntl = 0; ntl < 4; ++ntl) {
        acc[mtl][ntl] = __builtin_amdgcn_mfma_f32_16x16x32_bf16(ah, bh[ntl], acc[mtl][ntl], 0, 0, 0);
        acc[mtl][ntl] = __builtin_amdgcn_mfma_f32_16x16x32_bf16(ah, bl[ntl], acc[mtl][ntl], 0, 0, 0);
        acc[mtl][ntl] = __builtin_amdgcn_mfma_f32_16x16x32_bf16(al, bh[ntl], acc[mtl][ntl], 0, 0, 0);
      }
    }
  }

  // epilogue: relu(acc + b1[n]) * w2[n], reduce over the 16-lane n groups
  float b1v[4], w2v[4];
#pragma unroll
  for (int ntl = 0; ntl < 4; ++ntl) {
    int n = (wc * 4 + ntl) * 16 + l15;
    b1v[ntl] = b1[n]; w2v[ntl] = w2[n];
  }
  float v[4][4];
#pragma unroll
  for (int mtl = 0; mtl < 4; ++mtl)
#pragma unroll
    for (int reg = 0; reg < 4; ++reg) {
      float pv = 0.f;
#pragma unroll
      for (int ntl = 0; ntl < 4; ++ntl) {
        float h = acc[mtl][ntl][reg] + b1v[ntl];
        h = h > 0.f ? h : 0.f;
        pv = fmaf(h, w2v[ntl], pv);
      }
      v[mtl][reg] = pv;
    }
#pragma unroll
  for (int mask = 1; mask < 16; mask <<= 1)
#pragma unroll
    for (int mtl = 0; mtl < 4; ++mtl)
#pragma unroll
      for (int reg = 0; reg < 4; ++reg)
        v[mtl][reg] += __shfl_xor(v[mtl][reg], mask);

  if (l15 == 0) {
#pragma unroll
    for (int mtl = 0; mtl < 4; ++mtl)
#pragma unroll
      for (int reg = 0; reg < 4; ++reg)
        part[wave][mtl * 16 + quad * 4 + reg] = v[mtl][reg];
  }
  __syncthreads();

  // fused: logits -> z (gumbel), sigmoid partial sum (f64) + z-max per 64 tokens
  if (tid < 128) {
    const int wgrp = tid >> 6;          // 0 or 1 (wave index among first two)
    const int token = m0 + tid;
    float L = part[wgrp * 2][tid & 63] + part[wgrp * 2 + 1][tid & 63] + b2[0];
    float g = -logf(-logf(u[token]));
    float z = L + g;                    // TAU = 1
    zout[token] = z;
    double s = (double)(1.f / (1.f + expf(-L)));
    float zm = z;
#pragma unroll
    for (int mask = 1; mask < 64; mask <<= 1) {
      s += __shfl_xor(s, mask);
      zm = fmaxf(zm, __shfl_xor(zm, mask));
    }
    if ((tid & 63) == 0) {
      int pidx = blockIdx.x * 2 + wgrp;
      partS[pidx] = s;
      partM[pidx] = zm;
    }
  }
}

// ---------------------------------------------------------------------------
// Softmax: grid=8 (one block/row), 1024 thr. Shfl-tree reductions only
// (deterministic fixed order). Also finalizes expected_k / k.
// ---------------------------------------------------------------------------
__global__ __launch_bounds__(1024) void softmax_kernel(
    const float* __restrict__ z, const double* __restrict__ partS,
    const float* __restrict__ partM, float* __restrict__ soft,
    int* __restrict__ krow, float* __restrict__ ek_out)
{
  const int b = blockIdx.x;
  const int t = threadIdx.x;
  __shared__ float m_sh;
  __shared__ double ek_sh;
  __shared__ double wp[16];
  __shared__ float den_sh;

  if (t < 64) {
    double ps = partS[b * 64 + t];
    float  pm = partM[b * 64 + t];
#pragma unroll
    for (int mask = 1; mask < 64; mask <<= 1) {
      ps += __shfl_xor(ps, mask);
      pm = fmaxf(pm, __shfl_xor(pm, mask));
    }
    if (t == 0) { ek_sh = ps; m_sh = pm; }
  }
  __syncthreads();
  float m = m_sh;

  float e[4];
  double pe = 0.0;
#pragma unroll
  for (int i = 0; i < 4; ++i) {
    e[i] = expf(z[b * S_ + t + i * 1024] - m);
    pe += (double)e[i];
  }
#pragma unroll
  for (int mask = 1; mask < 64; mask <<= 1) pe += __shfl_xor(pe, mask);
  if ((t & 63) == 0) wp[t >> 6] = pe;
  __syncthreads();
  if (t < 16) {
    double vv = wp[t];
#pragma unroll
    for (int mask = 1; mask < 16; mask <<= 1) vv += __shfl_xor(vv, mask);
    if (t == 0) den_sh = (float)vv;
  }
  __syncthreads();
  float den = den_sh;
#pragma unroll
  for (int i = 0; i < 4; ++i) soft[b * S_ + t + i * 1024] = e[i] / den;

  if (t == 0) {
    float ekf = (float)ek_sh;
    int k = (int)ekf;                   // astype(int32): trunc
    if (k < MIN_K) k = MIN_K;
    krow[b] = k;
    ek_out[b] = ekf;
  }
}

// ---------------------------------------------------------------------------
// Rank partial: grid (16 i-chunks, 4 j-chunks, 8 rows), int atomicAdd
// (deterministic). Exact stable-argsort rank semantics.
// ---------------------------------------------------------------------------
__global__ __launch_bounds__(256) void rank_kernel(
    const float* __restrict__ soft, int* __restrict__ counts)
{
  __shared__ float4 sjs[256];
  const int b  = blockIdx.z;
  const int ic = blockIdx.x;
  const int jc = blockIdx.y;
  const int tid = threadIdx.x;
  const float* row = soft + b * S_;

  sjs[tid] = ((const float4*)row)[jc * 256 + tid];
  const int i = ic * 256 + tid;
  const float si = row[i];
  __syncthreads();

  int cnt = 0;
  const int jbase = jc * 1024;
  for (int j4 = 0; j4 < 256; ++j4) {
    float4 vv = sjs[j4];
    int j = jbase + j4 * 4;
    cnt += (vv.x > si) || (vv.x == si && (j + 0) < i);
    cnt += (vv.y > si) || (vv.y == si && (j + 1) < i);
    cnt += (vv.z > si) || (vv.z == si && (j + 2) < i);
    cnt += (vv.w > si) || (vv.w == si && (j + 3) < i);
  }
  atomicAdd(&counts[b * S_ + i], cnt);
}

// ---------------------------------------------------------------------------
// Filter + mask finalize. sel is EXACTLY +0 for dropped tokens ((0-s)+s == +0
// in RNE), so skip the x read for those blocks (saves ~half the fetch).
// ---------------------------------------------------------------------------
__global__ __launch_bounds__(256) void filter_kernel(
    const float* __restrict__ x, const float* __restrict__ soft,
    const int* __restrict__ counts, const int* __restrict__ krow,
    float* __restrict__ out, float* __restrict__ mask_out)
{
  const int token = blockIdx.x;           // 0..32767
  const int b = token >> 12;              // S_=4096
  const float s = soft[token];
  const float h = (counts[token] < krow[b]) ? 1.f : 0.f;
  const float sel = (h - s) + s;

  size_t base = (size_t)token * (E_ / 4) + threadIdx.x;
  if (sel == 0.f) {
    ((float4*)out)[base] = make_float4(0.f, 0.f, 0.f, 0.f);
  } else {
    float4 v = ((const float4*)x)[base];
    v.x *= sel; v.y *= sel; v.z *= sel; v.w *= sel;
    ((float4*)out)[base] = v;
  }
  if (threadIdx.x == 0) mask_out[token] = sel;
}

// ---------------------------------------------------------------------------
extern "C" void kernel_launch(void* const* d_in, const int* in_sizes, int n_in,
                              void* d_out, int out_size, void* d_ws, size_t ws_size,
                              hipStream_t stream) {
  const float* x  = (const float*)d_in[0];
  const float* w1 = (const float*)d_in[1];
  const float* b1 = (const float*)d_in[2];
  const float* w2 = (const float*)d_in[3];
  const float* b2 = (const float*)d_in[4];
  const float* u  = (const float*)d_in[5];

  float* out = (float*)d_out;
  float* out_filt = out;
  float* out_mask = out + OUT_MASK_OFF;
  float* out_ek   = out + OUT_EK_OFF;

  char* ws = (char*)d_ws;
  float*          ws_z      = (float*)(ws + Z_OFF);
  float*          ws_soft   = (float*)(ws + SOFT_OFF);
  int*            ws_cnt    = (int*)(ws + CNT_OFF);
  int*            ws_krow   = (int*)(ws + KROW_OFF);
  double*         ws_partS  = (double*)(ws + PARTS_OFF);
  float*          ws_partM  = (float*)(ws + PARTM_OFF);
  unsigned short* ws_w1thi  = (unsigned short*)(ws + W1T_HI_OFF);
  unsigned short* ws_w1tlo  = (unsigned short*)(ws + W1T_LO_OFF);

  hipMemsetAsync(ws_cnt, 0, B_ * S_ * sizeof(int), stream);
  prep_w_kernel<<<dim3(128), dim3(256), 0, stream>>>(w1, ws_w1thi, ws_w1tlo);
  scorer_kernel<<<dim3(B_ * S_ / 128), dim3(256), 0, stream>>>(
      x, ws_w1thi, ws_w1tlo, b1, w2, b2, u, ws_z, ws_partS, ws_partM);
  softmax_kernel<<<dim3(B_), dim3(1024), 0, stream>>>(
      ws_z, ws_partS, ws_partM, ws_soft, ws_krow, out_ek);
  rank_kernel<<<dim3(16, 4, 8), dim3(256), 0, stream>>>(ws_soft, ws_cnt);
  filter_kernel<<<dim3(B_ * S_), dim3(256), 0, stream>>>(
      x, ws_soft, ws_cnt, ws_krow, out_filt, out_mask);
}

// Round 4
// 337.449 us; speedup vs baseline: 1.0266x; 1.0266x over previous
//
#include <hip/hip_runtime.h>
#include <hip/hip_bf16.h>
#include <math.h>

// Problem constants
#define B_ 8
#define S_ 4096
#define E_ 1024
#define H_ 128
#define MIN_K 32
// d_out layout: filtered [B,S,E] | selection_mask [B,S] | expected_k [B]
#define OUT_MASK_OFF (B_*S_*E_)
#define OUT_EK_OFF   (B_*S_*E_ + B_*S_)

// workspace byte offsets
#define Z_OFF      0
#define SOFT_OFF   131072
#define CNT_OFF    262144
#define KROW_OFF   393216
#define PARTS_OFF  393248   // 1024 doubles (8-aligned)
#define PARTM_OFF  401440   // 1024 floats
#define W1T_HI_OFF 405536   // 16-aligned
#define W1T_LO_OFF 667680   // 16-aligned

typedef __attribute__((ext_vector_type(8))) short   frag8;   // 8 bf16 (4 VGPR)
typedef __attribute__((ext_vector_type(4))) float   fragc;   // 4 f32 acc
typedef __attribute__((ext_vector_type(4))) unsigned short us4;

static __device__ __forceinline__ unsigned short bf16_rne(float f) {
  unsigned u = __float_as_uint(f);
  unsigned r = u + 0x7FFF + ((u >> 16) & 1);
  return (unsigned short)(r >> 16);
}
static __device__ __forceinline__ float bf16_to_f32(unsigned short h) {
  return __uint_as_float(((unsigned)h) << 16);
}

// ---------------------------------------------------------------------------
// Prep: w1 [E][H] f32 -> w1t_hi/lo [H][E] bf16 (transposed, k-contiguous)
// ---------------------------------------------------------------------------
__global__ __launch_bounds__(256) void prep_w_kernel(
    const float* __restrict__ w1,
    unsigned short* __restrict__ w1t_hi, unsigned short* __restrict__ w1t_lo)
{
  int id = blockIdx.x * 256 + threadIdx.x;       // 0..32767
  int k  = id >> 5;                               // 0..1023
  int n4 = id & 31;                               // 0..31
  float4 w = *(const float4*)(w1 + k * H_ + n4 * 4);
#pragma unroll
  for (int e = 0; e < 4; ++e) {
    float f = (e == 0) ? w.x : (e == 1) ? w.y : (e == 2) ? w.z : w.w;
    unsigned short hi = bf16_rne(f);
    unsigned short lo = bf16_rne(f - bf16_to_f32(hi));
    int n = n4 * 4 + e;
    w1t_hi[n * E_ + k] = hi;
    w1t_lo[n * E_ + k] = lo;
  }
}

// ---------------------------------------------------------------------------
// Scorer: split-bf16 MFMA (3 products). SMALL tile for occupancy:
// M=32, N=128(full), KT=64, grid 1024 (4 blocks/CU), 4 waves/block.
// Wave w: n in [32w, 32w+32) (nt=2); mt=2 m-tiles shared by all waves.
// A staged via LDS (9.7 KB only); B read directly from w1t (L1/L2-hot)
// -> no B staging writes, no B bank conflicts. 16 K-iterations.
// Epilogue fuses logit reduce + gumbel z + sigmoid/max partials.
// ---------------------------------------------------------------------------
#define KT 64
#define LDST 72   // shorts; 144 B row stride (16B-aligned, ~2-way banks on frag reads)

__global__ __launch_bounds__(256) void scorer_kernel(
    const float* __restrict__ x,
    const unsigned short* __restrict__ w1t_hi,
    const unsigned short* __restrict__ w1t_lo,
    const float* __restrict__ b1, const float* __restrict__ w2,
    const float* __restrict__ b2, const float* __restrict__ u,
    float* __restrict__ zout, double* __restrict__ partS,
    float* __restrict__ partM)
{
  __shared__ unsigned short xs_hi[32 * LDST];
  __shared__ unsigned short xs_lo[32 * LDST];
  __shared__ float part[4][32];

  const int tid  = threadIdx.x;
  const int wave = tid >> 6;
  const int lane = tid & 63;
  const int l15  = lane & 15;
  const int quad = lane >> 4;
  const int m0   = blockIdx.x * 32;

  fragc acc[2][2];
#pragma unroll
  for (int i = 0; i < 2; ++i)
#pragma unroll
    for (int j = 0; j < 2; ++j) acc[i][j] = (fragc)(0.f);

  // x staging: 512 float4 per K-tile (32 rows x 16 float4), 2 per thread
  int sm[2], skq[2];
#pragma unroll
  for (int i = 0; i < 2; ++i) { int idx = tid + i * 256; sm[i] = idx >> 4; skq[i] = idx & 15; }

  float4 p[2];
#pragma unroll
  for (int i = 0; i < 2; ++i)
    p[i] = *(const float4*)(x + (size_t)(m0 + sm[i]) * E_ + skq[i] * 4);

  for (int k0 = 0; k0 < E_; k0 += KT) {
    __syncthreads();   // previous tile consumed
#pragma unroll
    for (int i = 0; i < 2; ++i) {
      us4 h4, l4;
      float fv[4] = {p[i].x, p[i].y, p[i].z, p[i].w};
#pragma unroll
      for (int e = 0; e < 4; ++e) {
        unsigned short hi = bf16_rne(fv[e]);
        h4[e] = hi; l4[e] = bf16_rne(fv[e] - bf16_to_f32(hi));
      }
      *(us4*)&xs_hi[sm[i] * LDST + skq[i] * 4] = h4;
      *(us4*)&xs_lo[sm[i] * LDST + skq[i] * 4] = l4;
    }
    __syncthreads();

    if (k0 + KT < E_) {
#pragma unroll
      for (int i = 0; i < 2; ++i)
        p[i] = *(const float4*)(x + (size_t)(m0 + sm[i]) * E_ + (k0 + KT) + skq[i] * 4);
    }

#pragma unroll
    for (int ks = 0; ks < 2; ++ks) {          // two 16x16x32 K-steps per tile
      frag8 ah[2], al[2];
#pragma unroll
      for (int mt = 0; mt < 2; ++mt) {
        int a = (mt * 16 + l15) * LDST + ks * 32 + quad * 8;
        ah[mt] = *(const frag8*)&xs_hi[a];
        al[mt] = *(const frag8*)&xs_lo[a];
      }
#pragma unroll
      for (int nt = 0; nt < 2; ++nt) {
        int n = wave * 32 + nt * 16 + l15;
        size_t off = (size_t)n * E_ + k0 + ks * 32 + quad * 8;
        frag8 bh = *(const frag8*)(w1t_hi + off);
        frag8 bl = *(const frag8*)(w1t_lo + off);
#pragma unroll
        for (int mt = 0; mt < 2; ++mt) {
          acc[mt][nt] = __builtin_amdgcn_mfma_f32_16x16x32_bf16(ah[mt], bh, acc[mt][nt], 0, 0, 0);
          acc[mt][nt] = __builtin_amdgcn_mfma_f32_16x16x32_bf16(ah[mt], bl, acc[mt][nt], 0, 0, 0);
          acc[mt][nt] = __builtin_amdgcn_mfma_f32_16x16x32_bf16(al[mt], bh, acc[mt][nt], 0, 0, 0);
        }
      }
    }
  }

  // epilogue: relu(acc + b1[n]) * w2[n], reduce over this wave's 32 n
  float b1v[2], w2v[2];
#pragma unroll
  for (int nt = 0; nt < 2; ++nt) {
    int n = wave * 32 + nt * 16 + l15;
    b1v[nt] = b1[n]; w2v[nt] = w2[n];
  }
  float v[2][4];
#pragma unroll
  for (int mt = 0; mt < 2; ++mt)
#pragma unroll
    for (int reg = 0; reg < 4; ++reg) {
      float pv = 0.f;
#pragma unroll
      for (int nt = 0; nt < 2; ++nt) {
        float h = acc[mt][nt][reg] + b1v[nt];
        h = h > 0.f ? h : 0.f;
        pv = fmaf(h, w2v[nt], pv);
      }
      v[mt][reg] = pv;
    }
#pragma unroll
  for (int mask = 1; mask < 16; mask <<= 1)
#pragma unroll
    for (int mt = 0; mt < 2; ++mt)
#pragma unroll
      for (int reg = 0; reg < 4; ++reg)
        v[mt][reg] += __shfl_xor(v[mt][reg], mask);

  if (l15 == 0) {
#pragma unroll
    for (int mt = 0; mt < 2; ++mt)
#pragma unroll
      for (int reg = 0; reg < 4; ++reg)
        part[wave][mt * 16 + quad * 4 + reg] = v[mt][reg];
  }
  __syncthreads();

  // fused: logits -> z (gumbel), sigmoid f64 partial + z-max for 32 tokens
  if (tid < 32) {
    const int token = m0 + tid;
    float L = ((part[0][tid] + part[1][tid]) + (part[2][tid] + part[3][tid])) + b2[0];
    float g = -logf(-logf(u[token]));
    float z = L + g;                    // TAU = 1
    zout[token] = z;
    double s = (double)(1.f / (1.f + expf(-L)));
    float zm = z;
#pragma unroll
    for (int mask = 1; mask < 32; mask <<= 1) {
      s += __shfl_xor(s, mask);
      zm = fmaxf(zm, __shfl_xor(zm, mask));
    }
    if (tid == 0) {
      partS[blockIdx.x] = s;
      partM[blockIdx.x] = zm;
    }
  }
}

// ---------------------------------------------------------------------------
// Softmax: grid=8 (one block/row), 1024 thr. 128 partials per row.
// Shfl-tree reductions (deterministic). Finalizes expected_k / k.
// ---------------------------------------------------------------------------
__global__ __launch_bounds__(1024) void softmax_kernel(
    const float* __restrict__ z, const double* __restrict__ partS,
    const float* __restrict__ partM, float* __restrict__ soft,
    int* __restrict__ krow, float* __restrict__ ek_out)
{
  const int b = blockIdx.x;
  const int t = threadIdx.x;
  __shared__ double sS[2];
  __shared__ float  sM[2];
  __shared__ double wp[16];
  __shared__ float den_sh;

  if (t < 128) {
    double ps = partS[b * 128 + t];
    float  pm = partM[b * 128 + t];
#pragma unroll
    for (int mask = 1; mask < 64; mask <<= 1) {
      ps += __shfl_xor(ps, mask);
      pm = fmaxf(pm, __shfl_xor(pm, mask));
    }
    if ((t & 63) == 0) { sS[t >> 6] = ps; sM[t >> 6] = pm; }
  }
  __syncthreads();
  const float m = fmaxf(sM[0], sM[1]);

  float e[4];
  double pe = 0.0;
#pragma unroll
  for (int i = 0; i < 4; ++i) {
    e[i] = expf(z[b * S_ + t + i * 1024] - m);
    pe += (double)e[i];
  }
#pragma unroll
  for (int mask = 1; mask < 64; mask <<= 1) pe += __shfl_xor(pe, mask);
  if ((t & 63) == 0) wp[t >> 6] = pe;
  __syncthreads();
  if (t < 16) {
    double vv = wp[t];
#pragma unroll
    for (int mask = 1; mask < 16; mask <<= 1) vv += __shfl_xor(vv, mask);
    if (t == 0) den_sh = (float)vv;
  }
  __syncthreads();
  float den = den_sh;
#pragma unroll
  for (int i = 0; i < 4; ++i) soft[b * S_ + t + i * 1024] = e[i] / den;

  if (t == 0) {
    float ekf = (float)(sS[0] + sS[1]);
    int k = (int)ekf;                   // astype(int32): trunc
    if (k < MIN_K) k = MIN_K;
    krow[b] = k;
    ek_out[b] = ekf;
  }
}

// ---------------------------------------------------------------------------
// Rank partial: grid (16 i-chunks, 4 j-chunks, 8 rows), int atomicAdd
// (deterministic). Exact stable-argsort rank semantics.
// ---------------------------------------------------------------------------
__global__ __launch_bounds__(256) void rank_kernel(
    const float* __restrict__ soft, int* __restrict__ counts)
{
  __shared__ float4 sjs[256];
  const int b  = blockIdx.z;
  const int ic = blockIdx.x;
  const int jc = blockIdx.y;
  const int tid = threadIdx.x;
  const float* row = soft + b * S_;

  sjs[tid] = ((const float4*)row)[jc * 256 + tid];
  const int i = ic * 256 + tid;
  const float si = row[i];
  __syncthreads();

  int cnt = 0;
  const int jbase = jc * 1024;
  for (int j4 = 0; j4 < 256; ++j4) {
    float4 vv = sjs[j4];
    int j = jbase + j4 * 4;
    cnt += (vv.x > si) || (vv.x == si && (j + 0) < i);
    cnt += (vv.y > si) || (vv.y == si && (j + 1) < i);
    cnt += (vv.z > si) || (vv.z == si && (j + 2) < i);
    cnt += (vv.w > si) || (vv.w == si && (j + 3) < i);
  }
  atomicAdd(&counts[b * S_ + i], cnt);
}

// ---------------------------------------------------------------------------
// Filter + mask finalize. sel is EXACTLY +0 for dropped tokens ((0-s)+s == +0
// in RNE), so skip the x read for those blocks (saves ~half the fetch).
// ---------------------------------------------------------------------------
__global__ __launch_bounds__(256) void filter_kernel(
    const float* __restrict__ x, const float* __restrict__ soft,
    const int* __restrict__ counts, const int* __restrict__ krow,
    float* __restrict__ out, float* __restrict__ mask_out)
{
  const int token = blockIdx.x;           // 0..32767
  const int b = token >> 12;              // S_=4096
  const float s = soft[token];
  const float h = (counts[token] < krow[b]) ? 1.f : 0.f;
  const float sel = (h - s) + s;

  size_t base = (size_t)token * (E_ / 4) + threadIdx.x;
  if (sel == 0.f) {
    ((float4*)out)[base] = make_float4(0.f, 0.f, 0.f, 0.f);
  } else {
    float4 v = ((const float4*)x)[base];
    v.x *= sel; v.y *= sel; v.z *= sel; v.w *= sel;
    ((float4*)out)[base] = v;
  }
  if (threadIdx.x == 0) mask_out[token] = sel;
}

// ---------------------------------------------------------------------------
extern "C" void kernel_launch(void* const* d_in, const int* in_sizes, int n_in,
                              void* d_out, int out_size, void* d_ws, size_t ws_size,
                              hipStream_t stream) {
  const float* x  = (const float*)d_in[0];
  const float* w1 = (const float*)d_in[1];
  const float* b1 = (const float*)d_in[2];
  const float* w2 = (const float*)d_in[3];
  const float* b2 = (const float*)d_in[4];
  const float* u  = (const float*)d_in[5];

  float* out = (float*)d_out;
  float* out_filt = out;
  float* out_mask = out + OUT_MASK_OFF;
  float* out_ek   = out + OUT_EK_OFF;

  char* ws = (char*)d_ws;
  float*          ws_z      = (float*)(ws + Z_OFF);
  float*          ws_soft   = (float*)(ws + SOFT_OFF);
  int*            ws_cnt    = (int*)(ws + CNT_OFF);
  int*            ws_krow   = (int*)(ws + KROW_OFF);
  double*         ws_partS  = (double*)(ws + PARTS_OFF);
  float*          ws_partM  = (float*)(ws + PARTM_OFF);
  unsigned short* ws_w1thi  = (unsigned short*)(ws + W1T_HI_OFF);
  unsigned short* ws_w1tlo  = (unsigned short*)(ws + W1T_LO_OFF);

  hipMemsetAsync(ws_cnt, 0, B_ * S_ * sizeof(int), stream);
  prep_w_kernel<<<dim3(128), dim3(256), 0, stream>>>(w1, ws_w1thi, ws_w1tlo);
  scorer_kernel<<<dim3(B_ * S_ / 32), dim3(256), 0, stream>>>(
      x, ws_w1thi, ws_w1tlo, b1, w2, b2, u, ws_z, ws_partS, ws_partM);
  softmax_kernel<<<dim3(B_), dim3(1024), 0, stream>>>(
      ws_z, ws_partS, ws_partM, ws_soft, ws_krow, out_ek);
  rank_kernel<<<dim3(16, 4, 8), dim3(256), 0, stream>>>(ws_soft, ws_cnt);
  filter_kernel<<<dim3(B_ * S_), dim3(256), 0, stream>>>(
      x, ws_soft, ws_cnt, ws_krow, out_filt, out_mask);
}